// Round 15
// baseline (802.533 us; speedup 1.0000x reference)
//
#include <hip/hip_runtime.h>
#include <stdint.h>

// ---------------- problem constants ----------------
#define NODES   20001
#define EMB     128
#define HID     256
#define BROWS   8192
#define NWORLD  16

// ---------------- GEMM tiling ----------------
#define BM 64                              // rows per mtile (4-wave blocks)
#define CHN 1280                           // nodes per block strip (10 sub-tiles)
#define CHUNKS 16                          // 16*1280 = 20480 >= 20001
#define MAXMT  (BROWS / BM + NWORLD)       // 144

// ---------------- workspace layout (bytes) ----------------
#define WS_H    0                          // bf16 h [8192][256] = 4 MB
#define WS_SORT (4194304)                  // int sorted_rows[10240]
#define WS_CNT  (WS_SORT + 10240 * 4)      // int counts[16]
#define WS_CUR  (WS_CNT + 64)              // int cursors[16]
#define WS_PFX  (WS_CUR + 64)              // int pprefix[16]
#define WS_MTW  (WS_PFX + 64)              // int mt_world[160]
#define WS_MTB  (WS_MTW + 640)             // int mt_base[160]
#define WS_MTV  (WS_MTB + 640)             // int mt_valid[160]
#define WS_NMT  (WS_MTV + 640)             // int n_mtiles
#define WS_CTRL_BYTES (WS_NMT + 4 - WS_SORT)

// ---------------- types ----------------
typedef __attribute__((ext_vector_type(8))) short          s8v;
typedef __attribute__((ext_vector_type(8))) unsigned short us8v;
typedef __attribute__((ext_vector_type(4))) unsigned short us4v;
typedef __attribute__((ext_vector_type(8))) __bf16         b8v;
typedef __attribute__((ext_vector_type(4))) float          f4v;

struct ABArg {
  us8v u;
  __device__ operator us8v() const { return u; }
  __device__ operator s8v()  const { return __builtin_bit_cast(s8v, u); }
  __device__ operator b8v()  const { return __builtin_bit_cast(b8v, u); }
};

static __device__ __forceinline__ f4v mfma16x16x32(us8v a, us8v b, f4v c) {
  return __builtin_amdgcn_mfma_f32_16x16x32_bf16(ABArg{a}, ABArg{b}, c, 0, 0, 0);
}

// f32 -> bf16 round-to-nearest-even
static __device__ __forceinline__ unsigned short f2b(float f) {
  unsigned u = __builtin_bit_cast(unsigned, f);
  u += 0x7FFFu + ((u >> 16) & 1u);
  return (unsigned short)(u >> 16);
}

static __device__ __forceinline__ us8v pack8(float4 a, float4 b) {
  us8v r;
  r[0] = f2b(a.x); r[1] = f2b(a.y); r[2] = f2b(a.z); r[3] = f2b(a.w);
  r[4] = f2b(b.x); r[5] = f2b(b.y); r[6] = f2b(b.z); r[7] = f2b(b.w);
  return r;
}

static __device__ __forceinline__ us4v pack4(float4 a) {
  us4v r;
  r[0] = f2b(a.x); r[1] = f2b(a.y); r[2] = f2b(a.z); r[3] = f2b(a.w);
  return r;
}

// ---------------- bucketing kernels ----------------
__global__ void k_hist(const int* __restrict__ ctx, int* __restrict__ counts) {
  int i = blockIdx.x * 256 + threadIdx.x;
  int w = ctx[i] - 1;
  w = w < 0 ? 0 : (w > 15 ? 15 : w);
  atomicAdd(&counts[w], 1);
}

__global__ void k_plan(const int* __restrict__ counts, int* __restrict__ pfx,
                       int* __restrict__ mtw, int* __restrict__ mtb,
                       int* __restrict__ mtv, int* __restrict__ nmt) {
  if (threadIdx.x != 0 || blockIdx.x != 0) return;
  int pbase = 0, total = 0;
  for (int w = 0; w < NWORLD; ++w) {
    int c = counts[w];
    pfx[w] = pbase;
    int tiles = (c + BM - 1) / BM;
    for (int t = 0; t < tiles; ++t) {
      mtw[total] = w;
      mtb[total] = pbase + t * BM;
      int v = c - t * BM;
      mtv[total] = v > BM ? BM : v;
      ++total;
    }
    pbase += tiles * BM;
  }
  *nmt = total;
}

__global__ void k_scatter(const int* __restrict__ ctx, const int* __restrict__ pfx,
                          int* __restrict__ cur, int* __restrict__ sorted) {
  int i = blockIdx.x * 256 + threadIdx.x;
  int w = ctx[i] - 1;
  w = w < 0 ? 0 : (w > 15 ? 15 : w);
  int pos = pfx[w] + atomicAdd(&cur[w], 1);
  sorted[pos] = i;
}

// ---------------- MLP (h = relu(relu(x W1^T + b1) W2^T + b2), bf16 out) ----------------
template <bool SWZOUT>
static __device__ __forceinline__ void mlp_layer(const unsigned short* aLds,
                                                 unsigned short* oLds,
                                                 const float* __restrict__ W,
                                                 const float* __restrict__ bias,
                                                 int lane, int j0) {
  f4v acc[4][4];
  const f4v fzero = {0.f, 0.f, 0.f, 0.f};
  for (int mf = 0; mf < 4; ++mf)
    for (int nf = 0; nf < 4; ++nf) acc[mf][nf] = fzero;

  for (int ks = 0; ks < 8; ++ks) {
    int kk = ks * 32 + ((lane >> 4) << 3);
    int cc = kk >> 3;
    us8v a[4], b[4];
    for (int nf = 0; nf < 4; ++nf) {
      int j = j0 + nf * 16 + (lane & 15);
      const float* wp = W + (size_t)j * 256 + kk;
      float4 u0 = *(const float4*)wp;
      float4 u1 = *(const float4*)(wp + 4);
      b[nf] = pack8(u0, u1);
    }
    for (int mf = 0; mf < 4; ++mf) {
      int row = mf * 16 + (lane & 15);
      a[mf] = *(const us8v*)((const char*)aLds + row * 512 + ((cc ^ (row & 7)) << 4));
    }
    for (int mf = 0; mf < 4; ++mf)
      for (int nf = 0; nf < 4; ++nf)
        acc[mf][nf] = mfma16x16x32(a[mf], b[nf], acc[mf][nf]);
  }

  for (int nf = 0; nf < 4; ++nf) {
    int j = j0 + nf * 16 + (lane & 15);
    float bv = bias[j];
    for (int mf = 0; mf < 4; ++mf) {
      for (int r = 0; r < 4; ++r) {
        int m = mf * 16 + ((lane >> 4) << 2) + r;
        float v = acc[mf][nf][r] + bv;
        v = v > 0.f ? v : 0.f;
        unsigned short hv = f2b(v);
        if (SWZOUT) {
          int byteoff = m * 512 + ((((j >> 3) ^ (m & 7))) << 4) + (j & 7) * 2;
          *(unsigned short*)((char*)oLds + byteoff) = hv;
        } else {
          *(unsigned short*)((char*)oLds + m * 512 + j * 2) = hv;
        }
      }
    }
  }
}

__global__ __launch_bounds__(256, 2) void k_mlp(
    const int* __restrict__ source, const int* __restrict__ mode,
    const float* __restrict__ se, const float* __restrict__ me,
    const float* __restrict__ W1, const float* __restrict__ b1,
    const float* __restrict__ W2, const float* __restrict__ b2,
    unsigned short* __restrict__ hout) {
  __shared__ __align__(16) unsigned short xA[64 * 256];
  __shared__ __align__(16) unsigned short h1A[64 * 256];
  const int tid = threadIdx.x;
  const int lane = tid & 63;
  const int wid = tid >> 6;
  const int r0 = blockIdx.x * 64;

  {
    int rl = tid >> 2, part = tid & 3;
    int row = r0 + rl;
    const float* src = (part < 2) ? (se + (size_t)source[row] * EMB + part * 64)
                                  : (me + (size_t)mode[row] * EMB + (part - 2) * 64);
    for (int i = 0; i < 16; ++i) {
      float4 v = ((const float4*)src)[i];
      int c = part * 8 + (i >> 1);
      int byteoff = rl * 512 + ((c ^ (rl & 7)) << 4) + (i & 1) * 8;
      ushort4 bb;
      bb.x = f2b(v.x); bb.y = f2b(v.y); bb.z = f2b(v.z); bb.w = f2b(v.w);
      *(ushort4*)((char*)xA + byteoff) = bb;
    }
  }
  __syncthreads();

  const int j0 = wid * 64;
  mlp_layer<true>(xA, h1A, W1, b1, lane, j0);
  __syncthreads();
  mlp_layer<false>(h1A, xA, W2, b2, lane, j0);
  __syncthreads();

  {
    int rl = tid >> 2, part = tid & 3;
    const uint4* s = (const uint4*)((const char*)xA + rl * 512 + part * 128);
    uint4* d = (uint4*)((char*)(hout + (size_t)(r0 + rl) * 256) + part * 128);
    for (int i = 0; i < 8; ++i) d[i] = s[i];
  }
}

// ---------------- big head GEMM ----------------
// 4-wave (256-thread) blocks, BM=64, wave tile 16x128. Accumulate FOUR
// sub-tiles (512 cols) in AGPRs -> per-row NT stores are 2KB CONTIGUOUS
// (final notch of the confirmed write-granularity ladder). 256-thread
// blocks escape the 128-VGPR allocator wall (m97 precedent: 164+64 regs).
// BK=64 double-buffered bf16 B in LDS (2x16KB), coalesced B loads
// (4 nodes x 256B dense per instr), R11 pipeline, raw lgkm-only barriers.
__global__ __launch_bounds__(256, 1) void k_gemm(
    const unsigned short* __restrict__ h, const int* __restrict__ sorted,
    const int* __restrict__ mtw, const int* __restrict__ mtb,
    const int* __restrict__ mtv, const int* __restrict__ nmt,
    const float* __restrict__ headsW, const float* __restrict__ headsb,
    float* __restrict__ out) {
  const int y = blockIdx.y;                // mtile
  if (y >= *nmt) return;
  const int w = mtw[y];
  const int base = mtb[y];
  const int vcnt = mtv[y];
  const int chunk = blockIdx.x;
  const int cn0 = chunk * CHN;
  const int NT = min(10, (NODES - cn0 + 127) >> 7);
  const int S = NT * 4;                    // total k-steps (BK=64)

  __shared__ __align__(16) unsigned short Bs[2][128 * 64];  // 2 x 16 KB bf16
  __shared__ int rlArr[BM];
  float* stage = (float*)Bs[1];            // epilogue alias: 8 x 512 f32 = 16 KB

  const int tid = threadIdx.x;
  const int lane = tid & 63;
  const int wid = tid >> 6;                // 0..3; wave owns rows wid*16..+15

  if (tid < BM) rlArr[tid] = sorted[base + tid];

  // coalesced B staging: instr j covers 4 node rows' 256B f32 k-slices
  // densely (16 lanes x 16B per node). Thread's 8 pieces span 8 node groups.
  const int nj0 = wid * 32 + (lane >> 4);  // node offset for j*4
  const int piece = lane & 15;
  const size_t hb = (size_t)w * NODES;

  float4 pf[8];                            // in-flight B batch (8 x 16B)
  auto issue = [&](int s) {
    const int ts = s >> 2, ks4 = s & 3;
#pragma unroll
    for (int j = 0; j < 8; ++j) {
      int ng = cn0 + ts * 128 + nj0 + j * 4;
      ng = ng < NODES ? ng : NODES - 1;
      const float* p = headsW + (hb + (size_t)ng) * 256 + ks4 * 64 + piece * 4;
      pf[j] = *(const float4*)p;
    }
  };
  auto bwrite = [&](int bufi) {
    char* Bd = (char*)Bs[bufi];
#pragma unroll
    for (int j = 0; j < 8; ++j) {
      int nloc = (nj0 & 127) + j * 4;      // 0..127 (wid*32 + lane>>4 + j*4)
      int c16 = piece >> 1;
      int cs = c16 ^ (nloc & 7);
      int byteoff = nloc * 128 + (cs << 4) + (piece & 1) * 8;
      *(us4v*)(Bd + byteoff) = pack4(pf[j]);
    }
  };

  // prologue
  issue(0);
  __syncthreads();                         // rlArr visible

  us8v aAll[8];                            // A fragments (16 rows, full K=256)
  {
    int rowm = wid * 16 + (lane & 15);
    const unsigned short* ab = h + (size_t)rlArr[rowm] * 256 + ((lane >> 4) << 3);
#pragma unroll
    for (int kc = 0; kc < 8; ++kc) aAll[kc] = *(const us8v*)(ab + kc * 32);
  }

  bwrite(0);
  issue(1);
  asm volatile("s_waitcnt lgkmcnt(0)" ::: "memory");
  __builtin_amdgcn_s_barrier();

  for (int g = 0; g * 4 < NT; ++g) {
    const int stc = min(4, NT - g * 4);    // sub-tiles in this group
    const int sBase = g * 16;
    f4v acc[4][8];                         // 128 AGPR: 4 sub-tiles x 8 nf
    {
      const f4v fzero = {0.f, 0.f, 0.f, 0.f};
#pragma unroll
      for (int st = 0; st < 4; ++st)
#pragma unroll
        for (int nf = 0; nf < 8; ++nf) acc[st][nf] = fzero;
    }

    // ---- k-loop over the group's sub-tiles (4 steps of BK=64 each) ----
#pragma unroll
    for (int st = 0; st < 4; ++st) {
      if (st < stc) {
#pragma unroll
        for (int ks4 = 0; ks4 < 4; ++ks4) {
          const int s = sBase + st * 4 + ks4;
          const char* Bb = (const char*)Bs[s & 1];
#pragma unroll
          for (int kc = 0; kc < 2; ++kc) {
            us8v b[8];
#pragma unroll
            for (int nf = 0; nf < 8; ++nf) {
              int node = nf * 16 + (lane & 15);
              int c16 = kc * 4 + (lane >> 4);
              b[nf] = *(const us8v*)(Bb + node * 128 + ((c16 ^ (node & 7)) << 4));
            }
#pragma unroll
            for (int nf = 0; nf < 8; ++nf)
              acc[st][nf] = mfma16x16x32(aAll[ks4 * 2 + kc], b[nf], acc[st][nf]);
          }
          // write pf(s+1) (issued one step ago), then issue pf(s+2)
          // (covered by the next step / the group epilogue)
          if (s + 1 < S) bwrite((s + 1) & 1);
          if (s + 2 < S) issue(s + 2);
          asm volatile("s_waitcnt lgkmcnt(0)" ::: "memory");
          __builtin_amdgcn_s_barrier();
        }
      }
    }
    // group's last step s_e = sBase + stc*4 - 1 is ODD -> Bs[1] dead; next
    // group's first buffer (Bs[0]) already prefetched. stage = Bs[1].

    // ---- group epilogue: 8 passes of 8 rows x 512 cols; per-row NT stores
    //      are 2KB contiguous ----
    const int gn0 = cn0 + g * 512;
    const bool fullG = (stc == 4) && (gn0 + 512 <= NODES);

    float bst[8];                          // bias for store cols j*64+lane
#pragma unroll
    for (int j = 0; j < 8; ++j) {
      int n = gn0 + j * 64 + lane;
      bst[j] = (j < stc * 2 && n < NODES) ? headsb[hb + n] : 0.f;
    }

#pragma unroll
    for (int p = 0; p < 8; ++p) {
      if (p) {  // stage readers of pass p-1 must finish before overwrite
        asm volatile("s_waitcnt lgkmcnt(0)" ::: "memory");
        __builtin_amdgcn_s_barrier();
      }
      // stage rows p*8..p*8+7 = wave p>>1, half-wave p&1
      if (wid == (p >> 1) && (lane >> 5) == (p & 1)) {
        int q = (lane >> 4) & 1;
#pragma unroll
        for (int st = 0; st < 4; ++st) {
          if (st < stc) {
#pragma unroll
            for (int nf = 0; nf < 8; ++nf)
#pragma unroll
              for (int r = 0; r < 4; ++r) {
                int row8 = q * 4 + r;                        // 0..7
                int col = st * 128 + nf * 16 + (lane & 15);  // 0..511
                stage[row8 * 512 + col] = acc[st][nf][r];
              }
          }
        }
      }
      asm volatile("s_waitcnt lgkmcnt(0)" ::: "memory");
      __builtin_amdgcn_s_barrier();
      // store: wave wid owns rows wid*2, wid*2+1; 8 NT instrs of 64
      // consecutive dwords each -> 2KB contiguous per row
#pragma unroll
      for (int rr = 0; rr < 2; ++rr) {
        int row8 = wid * 2 + rr;
        int m = p * 8 + row8;
        if (m < vcnt) {
          size_t ob = (size_t)rlArr[m] * NODES + gn0;
          const float* srow = &stage[row8 * 512];
          if (fullG) {
#pragma unroll
            for (int j = 0; j < 8; ++j)
              __builtin_nontemporal_store(srow[j * 64 + lane] + bst[j],
                                          &out[ob + j * 64 + lane]);
          } else {
#pragma unroll
            for (int j = 0; j < 8; ++j) {
              int col = j * 64 + lane;
              if (j < stc * 2 && gn0 + col < NODES)
                __builtin_nontemporal_store(srow[col] + bst[j], &out[ob + col]);
            }
          }
        }
      }
    }
    // stage (Bs[1]) must be free before next group's bwrite targets it
    asm volatile("s_waitcnt lgkmcnt(0)" ::: "memory");
    __builtin_amdgcn_s_barrier();
  }
}

// ---------------- launcher ----------------
extern "C" void kernel_launch(void* const* d_in, const int* in_sizes, int n_in,
                              void* d_out, int out_size, void* d_ws, size_t ws_size,
                              hipStream_t stream) {
  const int* source   = (const int*)d_in[0];
  const int* mode     = (const int*)d_in[1];
  const int* ctx      = (const int*)d_in[2];
  const float* se     = (const float*)d_in[3];
  const float* me     = (const float*)d_in[4];
  const float* W1     = (const float*)d_in[5];
  const float* b1     = (const float*)d_in[6];
  const float* W2     = (const float*)d_in[7];
  const float* b2     = (const float*)d_in[8];
  const float* headsW = (const float*)d_in[9];
  const float* headsb = (const float*)d_in[10];
  float* out = (float*)d_out;
  char* ws = (char*)d_ws;

  unsigned short* hbuf = (unsigned short*)(ws + WS_H);
  int* sorted = (int*)(ws + WS_SORT);
  int* counts = (int*)(ws + WS_CNT);
  int* cur    = (int*)(ws + WS_CUR);
  int* pfx    = (int*)(ws + WS_PFX);
  int* mtw    = (int*)(ws + WS_MTW);
  int* mtb    = (int*)(ws + WS_MTB);
  int* mtv    = (int*)(ws + WS_MTV);
  int* nmt    = (int*)(ws + WS_NMT);

  hipMemsetAsync(ws + WS_SORT, 0, WS_CTRL_BYTES, stream);

  k_hist<<<BROWS / 256, 256, 0, stream>>>(ctx, counts);
  k_plan<<<1, 64, 0, stream>>>(counts, pfx, mtw, mtb, mtv, nmt);
  k_scatter<<<BROWS / 256, 256, 0, stream>>>(ctx, pfx, cur, sorted);
  k_mlp<<<BROWS / 64, 256, 0, stream>>>(source, mode, se, me, W1, b1, W2, b2, hbuf);
  k_gemm<<<dim3(CHUNKS, MAXMT), 256, 0, stream>>>(hbuf, sorted, mtw, mtb, mtv, nmt,
                                                  headsW, headsb, out);
}

// Round 16
// 453.976 us; speedup vs baseline: 1.7678x; 1.7678x over previous
//
#include <hip/hip_runtime.h>
#include <stdint.h>

// ---------------- problem constants ----------------
#define NODES   20001
#define EMB     128
#define HID     256
#define BROWS   8192
#define NWORLD  16

// ---------------- GEMM tiling ----------------
#define BM 64                              // rows per mtile (4-wave blocks)
#define CHN 1280                           // nodes per block strip (10 sub-tiles)
#define CHUNKS 16                          // 16*1280 = 20480 >= 20001
#define MAXMT  (BROWS / BM + NWORLD)       // 144

// ---------------- workspace layout (bytes) ----------------
#define WS_H    0                          // bf16 h [8192][256] = 4 MB
#define WS_SORT (4194304)                  // int sorted_rows[10240]
#define WS_CNT  (WS_SORT + 10240 * 4)      // int counts[16]
#define WS_CUR  (WS_CNT + 64)              // int cursors[16]
#define WS_PFX  (WS_CUR + 64)              // int pprefix[16]
#define WS_MTW  (WS_PFX + 64)              // int mt_world[160]
#define WS_MTB  (WS_MTW + 640)             // int mt_base[160]
#define WS_MTV  (WS_MTB + 640)             // int mt_valid[160]
#define WS_NMT  (WS_MTV + 640)             // int n_mtiles
#define WS_CTRL_BYTES (WS_NMT + 4 - WS_SORT)

// ---------------- types ----------------
typedef __attribute__((ext_vector_type(8))) short          s8v;
typedef __attribute__((ext_vector_type(8))) unsigned short us8v;
typedef __attribute__((ext_vector_type(4))) unsigned short us4v;
typedef __attribute__((ext_vector_type(8))) __bf16         b8v;
typedef __attribute__((ext_vector_type(4))) float          f4v;

struct ABArg {
  us8v u;
  __device__ operator us8v() const { return u; }
  __device__ operator s8v()  const { return __builtin_bit_cast(s8v, u); }
  __device__ operator b8v()  const { return __builtin_bit_cast(b8v, u); }
};

static __device__ __forceinline__ f4v mfma16x16x32(us8v a, us8v b, f4v c) {
  return __builtin_amdgcn_mfma_f32_16x16x32_bf16(ABArg{a}, ABArg{b}, c, 0, 0, 0);
}

// f32 -> bf16 round-to-nearest-even
static __device__ __forceinline__ unsigned short f2b(float f) {
  unsigned u = __builtin_bit_cast(unsigned, f);
  u += 0x7FFFu + ((u >> 16) & 1u);
  return (unsigned short)(u >> 16);
}

static __device__ __forceinline__ us8v pack8(float4 a, float4 b) {
  us8v r;
  r[0] = f2b(a.x); r[1] = f2b(a.y); r[2] = f2b(a.z); r[3] = f2b(a.w);
  r[4] = f2b(b.x); r[5] = f2b(b.y); r[6] = f2b(b.z); r[7] = f2b(b.w);
  return r;
}

static __device__ __forceinline__ us4v pack4(float4 a) {
  us4v r;
  r[0] = f2b(a.x); r[1] = f2b(a.y); r[2] = f2b(a.z); r[3] = f2b(a.w);
  return r;
}

// ---------------- bucketing kernels ----------------
__global__ void k_hist(const int* __restrict__ ctx, int* __restrict__ counts) {
  int i = blockIdx.x * 256 + threadIdx.x;
  int w = ctx[i] - 1;
  w = w < 0 ? 0 : (w > 15 ? 15 : w);
  atomicAdd(&counts[w], 1);
}

__global__ void k_plan(const int* __restrict__ counts, int* __restrict__ pfx,
                       int* __restrict__ mtw, int* __restrict__ mtb,
                       int* __restrict__ mtv, int* __restrict__ nmt) {
  if (threadIdx.x != 0 || blockIdx.x != 0) return;
  int pbase = 0, total = 0;
  for (int w = 0; w < NWORLD; ++w) {
    int c = counts[w];
    pfx[w] = pbase;
    int tiles = (c + BM - 1) / BM;
    for (int t = 0; t < tiles; ++t) {
      mtw[total] = w;
      mtb[total] = pbase + t * BM;
      int v = c - t * BM;
      mtv[total] = v > BM ? BM : v;
      ++total;
    }
    pbase += tiles * BM;
  }
  *nmt = total;
}

__global__ void k_scatter(const int* __restrict__ ctx, const int* __restrict__ pfx,
                          int* __restrict__ cur, int* __restrict__ sorted) {
  int i = blockIdx.x * 256 + threadIdx.x;
  int w = ctx[i] - 1;
  w = w < 0 ? 0 : (w > 15 ? 15 : w);
  int pos = pfx[w] + atomicAdd(&cur[w], 1);
  sorted[pos] = i;
}

// ---------------- MLP (h = relu(relu(x W1^T + b1) W2^T + b2), bf16 out) ----------------
template <bool SWZOUT>
static __device__ __forceinline__ void mlp_layer(const unsigned short* aLds,
                                                 unsigned short* oLds,
                                                 const float* __restrict__ W,
                                                 const float* __restrict__ bias,
                                                 int lane, int j0) {
  f4v acc[4][4];
  const f4v fzero = {0.f, 0.f, 0.f, 0.f};
  for (int mf = 0; mf < 4; ++mf)
    for (int nf = 0; nf < 4; ++nf) acc[mf][nf] = fzero;

  for (int ks = 0; ks < 8; ++ks) {
    int kk = ks * 32 + ((lane >> 4) << 3);
    int cc = kk >> 3;
    us8v a[4], b[4];
    for (int nf = 0; nf < 4; ++nf) {
      int j = j0 + nf * 16 + (lane & 15);
      const float* wp = W + (size_t)j * 256 + kk;
      float4 u0 = *(const float4*)wp;
      float4 u1 = *(const float4*)(wp + 4);
      b[nf] = pack8(u0, u1);
    }
    for (int mf = 0; mf < 4; ++mf) {
      int row = mf * 16 + (lane & 15);
      a[mf] = *(const us8v*)((const char*)aLds + row * 512 + ((cc ^ (row & 7)) << 4));
    }
    for (int mf = 0; mf < 4; ++mf)
      for (int nf = 0; nf < 4; ++nf)
        acc[mf][nf] = mfma16x16x32(a[mf], b[nf], acc[mf][nf]);
  }

  for (int nf = 0; nf < 4; ++nf) {
    int j = j0 + nf * 16 + (lane & 15);
    float bv = bias[j];
    for (int mf = 0; mf < 4; ++mf) {
      for (int r = 0; r < 4; ++r) {
        int m = mf * 16 + ((lane >> 4) << 2) + r;
        float v = acc[mf][nf][r] + bv;
        v = v > 0.f ? v : 0.f;
        unsigned short hv = f2b(v);
        if (SWZOUT) {
          int byteoff = m * 512 + ((((j >> 3) ^ (m & 7))) << 4) + (j & 7) * 2;
          *(unsigned short*)((char*)oLds + byteoff) = hv;
        } else {
          *(unsigned short*)((char*)oLds + m * 512 + j * 2) = hv;
        }
      }
    }
  }
}

__global__ __launch_bounds__(256, 2) void k_mlp(
    const int* __restrict__ source, const int* __restrict__ mode,
    const float* __restrict__ se, const float* __restrict__ me,
    const float* __restrict__ W1, const float* __restrict__ b1,
    const float* __restrict__ W2, const float* __restrict__ b2,
    unsigned short* __restrict__ hout) {
  __shared__ __align__(16) unsigned short xA[64 * 256];
  __shared__ __align__(16) unsigned short h1A[64 * 256];
  const int tid = threadIdx.x;
  const int lane = tid & 63;
  const int wid = tid >> 6;
  const int r0 = blockIdx.x * 64;

  {
    int rl = tid >> 2, part = tid & 3;
    int row = r0 + rl;
    const float* src = (part < 2) ? (se + (size_t)source[row] * EMB + part * 64)
                                  : (me + (size_t)mode[row] * EMB + (part - 2) * 64);
    for (int i = 0; i < 16; ++i) {
      float4 v = ((const float4*)src)[i];
      int c = part * 8 + (i >> 1);
      int byteoff = rl * 512 + ((c ^ (rl & 7)) << 4) + (i & 1) * 8;
      ushort4 bb;
      bb.x = f2b(v.x); bb.y = f2b(v.y); bb.z = f2b(v.z); bb.w = f2b(v.w);
      *(ushort4*)((char*)xA + byteoff) = bb;
    }
  }
  __syncthreads();

  const int j0 = wid * 64;
  mlp_layer<true>(xA, h1A, W1, b1, lane, j0);
  __syncthreads();
  mlp_layer<false>(h1A, xA, W2, b2, lane, j0);
  __syncthreads();

  {
    int rl = tid >> 2, part = tid & 3;
    const uint4* s = (const uint4*)((const char*)xA + rl * 512 + part * 128);
    uint4* d = (uint4*)((char*)(hout + (size_t)(r0 + rl) * 256) + part * 128);
    for (int i = 0; i < 8; ++i) d[i] = s[i];
  }
}

// ---------------- big head GEMM ----------------
// R15 structure with TWO-sub-tile groups: 4-wave (256-thread) blocks, BM=64,
// wave tile 16x128, acc[2][8] = 64 AGPR + ~120 VGPR = ~185 unified regs ->
// 2 waves/SIMD -> TWO independent blocks co-resident per CU. Block A's
// store-heavy epilogue overlaps block B's load-heavy k-loop (the duty-cycle
// overlap single-block lockstep variants lacked). 1KB-contiguous NT row
// stores (confirmed granularity optimum; 2KB needs 260 regs -> occ 1).
__global__ __launch_bounds__(256, 2) void k_gemm(
    const unsigned short* __restrict__ h, const int* __restrict__ sorted,
    const int* __restrict__ mtw, const int* __restrict__ mtb,
    const int* __restrict__ mtv, const int* __restrict__ nmt,
    const float* __restrict__ headsW, const float* __restrict__ headsb,
    float* __restrict__ out) {
  const int y = blockIdx.y;                // mtile
  if (y >= *nmt) return;
  const int w = mtw[y];
  const int base = mtb[y];
  const int vcnt = mtv[y];
  const int chunk = blockIdx.x;
  const int cn0 = chunk * CHN;
  const int NT = min(10, (NODES - cn0 + 127) >> 7);
  const int S = NT * 4;                    // total k-steps (BK=64)

  __shared__ __align__(16) unsigned short Bs[2][128 * 64];  // 2 x 16 KB bf16
  __shared__ int rlArr[BM];
  float* stage = (float*)Bs[1];            // epilogue alias: 8 x 256 f32 = 8 KB

  const int tid = threadIdx.x;
  const int lane = tid & 63;
  const int wid = tid >> 6;                // 0..3; wave owns rows wid*16..+15

  if (tid < BM) rlArr[tid] = sorted[base + tid];

  // coalesced B staging: instr j covers 4 node rows' 256B f32 k-slices
  // densely (16 lanes x 16B per node).
  const int nj0 = wid * 32 + (lane >> 4);  // node offset for j*4
  const int piece = lane & 15;
  const size_t hb = (size_t)w * NODES;

  float4 pf[8];                            // in-flight B batch (8 x 16B)
  auto issue = [&](int s) {
    const int ts = s >> 2, ks4 = s & 3;
#pragma unroll
    for (int j = 0; j < 8; ++j) {
      int ng = cn0 + ts * 128 + nj0 + j * 4;
      ng = ng < NODES ? ng : NODES - 1;
      const float* p = headsW + (hb + (size_t)ng) * 256 + ks4 * 64 + piece * 4;
      pf[j] = *(const float4*)p;
    }
  };
  auto bwrite = [&](int bufi) {
    char* Bd = (char*)Bs[bufi];
#pragma unroll
    for (int j = 0; j < 8; ++j) {
      int nloc = (nj0 & 127) + j * 4;      // 0..127
      int c16 = piece >> 1;
      int cs = c16 ^ (nloc & 7);
      int byteoff = nloc * 128 + (cs << 4) + (piece & 1) * 8;
      *(us4v*)(Bd + byteoff) = pack4(pf[j]);
    }
  };

  // prologue
  issue(0);
  __syncthreads();                         // rlArr visible

  us8v aAll[8];                            // A fragments (16 rows, full K=256)
  {
    int rowm = wid * 16 + (lane & 15);
    const unsigned short* ab = h + (size_t)rlArr[rowm] * 256 + ((lane >> 4) << 3);
#pragma unroll
    for (int kc = 0; kc < 8; ++kc) aAll[kc] = *(const us8v*)(ab + kc * 32);
  }

  bwrite(0);
  issue(1);
  asm volatile("s_waitcnt lgkmcnt(0)" ::: "memory");
  __builtin_amdgcn_s_barrier();

  for (int g = 0; g * 2 < NT; ++g) {
    const int stc = min(2, NT - g * 2);    // sub-tiles in this group
    const int sBase = g * 8;
    f4v acc[2][8];                         // 64 AGPR: 2 sub-tiles x 8 nf
    {
      const f4v fzero = {0.f, 0.f, 0.f, 0.f};
#pragma unroll
      for (int st = 0; st < 2; ++st)
#pragma unroll
        for (int nf = 0; nf < 8; ++nf) acc[st][nf] = fzero;
    }

    // ---- k-loop over the group's sub-tiles (4 steps of BK=64 each) ----
#pragma unroll
    for (int st = 0; st < 2; ++st) {
      if (st < stc) {
#pragma unroll
        for (int ks4 = 0; ks4 < 4; ++ks4) {
          const int s = sBase + st * 4 + ks4;
          const char* Bb = (const char*)Bs[s & 1];
#pragma unroll
          for (int kc = 0; kc < 2; ++kc) {
            us8v b[8];
#pragma unroll
            for (int nf = 0; nf < 8; ++nf) {
              int node = nf * 16 + (lane & 15);
              int c16 = kc * 4 + (lane >> 4);
              b[nf] = *(const us8v*)(Bb + node * 128 + ((c16 ^ (node & 7)) << 4));
            }
#pragma unroll
            for (int nf = 0; nf < 8; ++nf)
              acc[st][nf] = mfma16x16x32(aAll[ks4 * 2 + kc], b[nf], acc[st][nf]);
          }
          // write pf(s+1) (issued one step ago), then issue pf(s+2)
          // (covered by the next step / the group epilogue)
          if (s + 1 < S) bwrite((s + 1) & 1);
          if (s + 2 < S) issue(s + 2);
          asm volatile("s_waitcnt lgkmcnt(0)" ::: "memory");
          __builtin_amdgcn_s_barrier();
        }
      }
    }
    // group's last step is ODD -> Bs[1] dead; next group's first buffer
    // (Bs[0]) already staged; pf holds the following step's data.

    // ---- group epilogue: 8 passes of 8 rows x 256 cols; per-row NT stores
    //      are 1KB contiguous ----
    const int gn0 = cn0 + g * 256;
    const bool fullG = (stc == 2) && (gn0 + 256 <= NODES);

    float bst[4];                          // bias for store cols j*64+lane
#pragma unroll
    for (int j = 0; j < 4; ++j) {
      int n = gn0 + j * 64 + lane;
      bst[j] = (j < stc * 2 && n < NODES) ? headsb[hb + n] : 0.f;
    }

#pragma unroll
    for (int p = 0; p < 8; ++p) {
      if (p) {  // stage readers of pass p-1 must finish before overwrite
        asm volatile("s_waitcnt lgkmcnt(0)" ::: "memory");
        __builtin_amdgcn_s_barrier();
      }
      // stage rows p*8..p*8+7 = wave p>>1, half-wave p&1
      if (wid == (p >> 1) && (lane >> 5) == (p & 1)) {
        int q = (lane >> 4) & 1;
#pragma unroll
        for (int st = 0; st < 2; ++st) {
          if (st < stc) {
#pragma unroll
            for (int nf = 0; nf < 8; ++nf)
#pragma unroll
              for (int r = 0; r < 4; ++r) {
                int row8 = q * 4 + r;                        // 0..7
                int col = st * 128 + nf * 16 + (lane & 15);  // 0..255
                stage[row8 * 256 + col] = acc[st][nf][r];
              }
          }
        }
      }
      asm volatile("s_waitcnt lgkmcnt(0)" ::: "memory");
      __builtin_amdgcn_s_barrier();
      // store: wave wid owns rows wid*2, wid*2+1; 4 NT instrs of 64
      // consecutive dwords each -> 1KB contiguous per row
#pragma unroll
      for (int rr = 0; rr < 2; ++rr) {
        int row8 = wid * 2 + rr;
        int m = p * 8 + row8;
        if (m < vcnt) {
          size_t ob = (size_t)rlArr[m] * NODES + gn0;
          const float* srow = &stage[row8 * 256];
          if (fullG) {
#pragma unroll
            for (int j = 0; j < 4; ++j)
              __builtin_nontemporal_store(srow[j * 64 + lane] + bst[j],
                                          &out[ob + j * 64 + lane]);
          } else {
#pragma unroll
            for (int j = 0; j < 4; ++j) {
              int col = j * 64 + lane;
              if (j < stc * 2 && gn0 + col < NODES)
                __builtin_nontemporal_store(srow[col] + bst[j], &out[ob + col]);
            }
          }
        }
      }
    }
    // stage (Bs[1]) must be free before next group's bwrite targets it
    asm volatile("s_waitcnt lgkmcnt(0)" ::: "memory");
    __builtin_amdgcn_s_barrier();
  }
}

// ---------------- launcher ----------------
extern "C" void kernel_launch(void* const* d_in, const int* in_sizes, int n_in,
                              void* d_out, int out_size, void* d_ws, size_t ws_size,
                              hipStream_t stream) {
  const int* source   = (const int*)d_in[0];
  const int* mode     = (const int*)d_in[1];
  const int* ctx      = (const int*)d_in[2];
  const float* se     = (const float*)d_in[3];
  const float* me     = (const float*)d_in[4];
  const float* W1     = (const float*)d_in[5];
  const float* b1     = (const float*)d_in[6];
  const float* W2     = (const float*)d_in[7];
  const float* b2     = (const float*)d_in[8];
  const float* headsW = (const float*)d_in[9];
  const float* headsb = (const float*)d_in[10];
  float* out = (float*)d_out;
  char* ws = (char*)d_ws;

  unsigned short* hbuf = (unsigned short*)(ws + WS_H);
  int* sorted = (int*)(ws + WS_SORT);
  int* counts = (int*)(ws + WS_CNT);
  int* cur    = (int*)(ws + WS_CUR);
  int* pfx    = (int*)(ws + WS_PFX);
  int* mtw    = (int*)(ws + WS_MTW);
  int* mtb    = (int*)(ws + WS_MTB);
  int* mtv    = (int*)(ws + WS_MTV);
  int* nmt    = (int*)(ws + WS_NMT);

  hipMemsetAsync(ws + WS_SORT, 0, WS_CTRL_BYTES, stream);

  k_hist<<<BROWS / 256, 256, 0, stream>>>(ctx, counts);
  k_plan<<<1, 64, 0, stream>>>(counts, pfx, mtw, mtb, mtv, nmt);
  k_scatter<<<BROWS / 256, 256, 0, stream>>>(ctx, pfx, cur, sorted);
  k_mlp<<<BROWS / 64, 256, 0, stream>>>(source, mode, se, me, W1, b1, W2, b2, hbuf);
  k_gemm<<<dim3(CHUNKS, MAXMT), 256, 0, stream>>>(hbuf, sorted, mtw, mtb, mtv, nmt,
                                                  headsW, headsb, out);
}